// Round 18
// baseline (287.959 us; speedup 1.0000x reference)
//
#include <hip/hip_runtime.h>

typedef unsigned int u32;
typedef __attribute__((ext_vector_type(4))) int i32x4;   // 16 i8 (A/B frag) or 4 i32 (C/D)

#define BM 256
#define BN 256
#define BKT 64    // K elements (i8) per K-tile; LDS row = 64 B, paired-row swizzle

__device__ __forceinline__ void gload16(const void* g, void* l) {
  __builtin_amdgcn_global_load_lds(
      (const __attribute__((address_space(1))) unsigned int*)g,
      (__attribute__((address_space(3))) unsigned int*)l, 16, 0, 0);
}

__device__ __forceinline__ u32 pack4_i8(float4 v, float scale) {
  const int a = (int)rintf(v.x / scale);
  const int b = (int)rintf(v.y / scale);
  const int c = (int)rintf(v.z / scale);
  const int d = (int)rintf(v.w / scale);
  return (u32)(a & 255) | (((u32)(b & 255)) << 8) |
         (((u32)(c & 255)) << 16) | (((u32)(d & 255)) << 24);
}

// ------- per-row fake-quant -> int8, single-pass, X and W merged in one grid -------
__global__ __launch_bounds__(256) void quant_rows4096_dual_kernel(
    const float* __restrict__ xsrc, const float* __restrict__ wsrc,
    u32* __restrict__ qx, u32* __restrict__ qw,
    float* __restrict__ sx, float* __restrict__ sw, int mrows)
{
  const int bid = (int)blockIdx.x;
  const float* __restrict__ src;
  u32* __restrict__ q;
  float* __restrict__ scales;
  size_t row;
  if (bid < mrows) { src = xsrc; q = qx; scales = sx; row = (size_t)bid; }
  else             { src = wsrc; q = qw; scales = sw; row = (size_t)(bid - mrows); }

  const float4* __restrict__ p = (const float4*)(src + row * 4096);
  const int t = threadIdx.x;
  float4 v0 = p[t];
  float4 v1 = p[t + 256];
  float4 v2 = p[t + 512];
  float4 v3 = p[t + 768];
  float m = 0.0f;
  m = fmaxf(m, fmaxf(fmaxf(fabsf(v0.x), fabsf(v0.y)), fmaxf(fabsf(v0.z), fabsf(v0.w))));
  m = fmaxf(m, fmaxf(fmaxf(fabsf(v1.x), fabsf(v1.y)), fmaxf(fabsf(v1.z), fabsf(v1.w))));
  m = fmaxf(m, fmaxf(fmaxf(fabsf(v2.x), fabsf(v2.y)), fmaxf(fabsf(v2.z), fabsf(v2.w))));
  m = fmaxf(m, fmaxf(fmaxf(fabsf(v3.x), fabsf(v3.y)), fmaxf(fabsf(v3.z), fabsf(v3.w))));
  #pragma unroll
  for (int off = 32; off > 0; off >>= 1) m = fmaxf(m, __shfl_xor(m, off));
  __shared__ float wmax[4];
  if ((t & 63) == 0) wmax[t >> 6] = m;
  __syncthreads();
  m = fmaxf(fmaxf(wmax[0], wmax[1]), fmaxf(wmax[2], wmax[3]));
  const float scale = fmaxf(m, 1e-5f) * (1.0f / 127.0f);
  if (t == 0) scales[row] = scale;
  u32* __restrict__ qp = q + row * 1024;
  qp[t]       = pack4_i8(v0, scale);
  qp[t + 256] = pack4_i8(v1, scale);
  qp[t + 512] = pack4_i8(v2, scale);
  qp[t + 768] = pack4_i8(v3, scale);
}

// generic fallback (any K multiple of 4)
__global__ __launch_bounds__(256) void quant_rows_kernel(
    const float* __restrict__ src, u32* __restrict__ q,
    float* __restrict__ scales, int K)
{
  const size_t row = blockIdx.x;
  const float* __restrict__ p = src + row * (size_t)K;
  const int t = threadIdx.x;
  const int nv = K >> 2;
  float m = 0.0f;
  for (int i = t; i < nv; i += 256) {
    float4 v = ((const float4*)p)[i];
    m = fmaxf(m, fmaxf(fmaxf(fabsf(v.x), fabsf(v.y)),
                       fmaxf(fabsf(v.z), fabsf(v.w))));
  }
  #pragma unroll
  for (int off = 32; off > 0; off >>= 1) m = fmaxf(m, __shfl_xor(m, off));
  __shared__ float wmax[4];
  if ((t & 63) == 0) wmax[t >> 6] = m;
  __syncthreads();
  m = fmaxf(fmaxf(wmax[0], wmax[1]), fmaxf(wmax[2], wmax[3]));
  const float scale = fmaxf(m, 1e-5f) * (1.0f / 127.0f);
  if (t == 0) scales[row] = scale;
  u32* __restrict__ qp = q + row * ((size_t)K >> 2);
  for (int i = t; i < nv; i += 256) {
    float4 v = ((const float4*)p)[i];
    qp[i] = pack4_i8(v, scale);
  }
}

// ------- 256x256 8-wave i8 GEMM, BK=64, quad-buffered LDS, 1 barrier/K-tile, -------
// ------- next-tile reads interleaved INTO the MFMA cluster (dbuf frag sets)   -------
// C = Aq(MxK) * Bq(NxK)^T, exact i32 accumulate via mfma_i32_16x16x64_i8.
// LDS: 4 slots x (A 256x64B + B 256x64B) = 128 KiB, paired-row swizzle:
//   physical 128B window = row-pair rp=r>>1; slot sp = ((c>>4)+((r&1)<<2)) ^ (rp&7).
// Window w: { STAGE4(tile w+3 -> slot (w+3)&3); VMW(8); BAR;
//             MFMA(mh0, set CUR) ; READS(tile w+1 -> set NXT) ; MFMA(mh1, CUR) }.
// Ledger identical to R13: 3 tiles x 4 ops in flight; VMW(8) at window w drains
// tile w+1, so its reads (issued AFTER BAR_w) follow their guarantee barrier —
// strictly cleaner than R13's pre-barrier reads. WAR: stage target slot
// (w+3)&3 = (w-1)&3 consumed in window w-1's MFMA region (lgkm before MFMA)
// before this wave issues STAGE4; cross-wave margin same class as R13
// (global-return latency >> residual ds_read latency). nK % 4 == 0, nK >= 8.
__global__ __launch_bounds__(512, 2) void gemm_bt_kernel(
    const signed char* __restrict__ Aq, const signed char* __restrict__ Bq,
    const float* __restrict__ sx, const float* __restrict__ sw,
    const float* __restrict__ bias, float* __restrict__ Y,
    unsigned int* __restrict__ rowmax, int M, int N, int K)
{
  __shared__ signed char lds[4][2][BM * 64];   // [slot][A/B], 16 KiB regions

  int bid = (int)blockIdx.x;
  const int nwg = (int)gridDim.x;
  if ((nwg & 7) == 0) {                 // bijective XCD swizzle
    const int cpx = nwg >> 3;
    bid = (bid & 7) * cpx + (bid >> 3);
  }
  const int ntile = N / BN;
  const size_t brow = (size_t)(bid / ntile) * BM;
  const size_t bcol = (size_t)(bid % ntile) * BN;

  const int t = threadIdx.x;
  const int lane = t & 63;
  const int wid = t >> 6;
  const int wr = wid >> 2, wc = wid & 3;       // 2(M) x 4(N) wave grid
  const int g4 = lane >> 4, l16 = lane & 15;

  // ds_read per-lane constants: parity = l16&1, w8 = (l16>>1)&7,
  // sp = (g4 + parity*4) ^ w8 ; byte = rp*128 + sp*16.
  const int parity = l16 & 1;
  const int w8 = (l16 >> 1) & 7;
  const int sp = (g4 + (parity << 2)) ^ w8;
  const int abase = (wr * 64 + (l16 >> 1)) * 128 + sp * 16;  // + mh*4096 + i*1024
  const int bbase = (wc * 32 + (l16 >> 1)) * 128 + sp * 16;  // + j*1024

  // staging: thread t -> linear LDS dst byte t*16 (+round*8192); inverse map:
  // q = (t&7) ^ ((t>>3)&7); row = 2*(t>>3) + (q>>2); col = (q&3)*16.
  const int q0 = (t & 7) ^ ((t >> 3) & 7);
  const int srow = 2 * (t >> 3) + (q0 >> 2);          // 0..127
  const int scol = (q0 & 3) * 16;
  const signed char* srcA = Aq + (brow + srow) * (size_t)K + scol;
  const signed char* srcB = Bq + (bcol + srow) * (size_t)K + scol;
  const int dstb = t * 16;

  i32x4 acc0[4][4] = {};   // mh0 (rows wr*128 + 0..63), exact i32
  i32x4 acc1[4][4] = {};   // mh1 (rows wr*128 + 64..127)
  const int nK = K / BKT;

  // double-buffered fragment sets (e = even windows, o = odd windows)
  i32x4 aAe0, aAe1, aAe2, aAe3, aCe0, aCe1, aCe2, aCe3, bAe0, bAe1, bAe2, bAe3;
  i32x4 aAo0, aAo1, aAo2, aAo3, aCo0, aCo1, aCo2, aCo3, bAo0, bAo1, bAo2, bAo3;

#define STAGE4(S, TT) do { \
    gload16(srcA + (size_t)(TT) * 64,                      &lds[S][0][dstb]); \
    gload16(srcA + 128 * (size_t)K + (size_t)(TT) * 64,    &lds[S][0][8192 + dstb]); \
    gload16(srcB + (size_t)(TT) * 64,                      &lds[S][1][dstb]); \
    gload16(srcB + 128 * (size_t)K + (size_t)(TT) * 64,    &lds[S][1][8192 + dstb]); \
  } while (0)
#define BARS() do { asm volatile("" ::: "memory"); \
                    __builtin_amdgcn_s_barrier(); \
                    asm volatile("" ::: "memory"); } while (0)
#define VMWS(NN) asm volatile("s_waitcnt vmcnt(" #NN ")" ::: "memory")
#define RDA(P, S, MH) do { \
    P##0 = *(const i32x4*)&lds[S][0][abase + (MH) * 4096 +    0]; \
    P##1 = *(const i32x4*)&lds[S][0][abase + (MH) * 4096 + 1024]; \
    P##2 = *(const i32x4*)&lds[S][0][abase + (MH) * 4096 + 2048]; \
    P##3 = *(const i32x4*)&lds[S][0][abase + (MH) * 4096 + 3072]; } while (0)
#define RDB(P, S) do { \
    P##0 = *(const i32x4*)&lds[S][1][bbase +    0]; \
    P##1 = *(const i32x4*)&lds[S][1][bbase + 1024]; \
    P##2 = *(const i32x4*)&lds[S][1][bbase + 2048]; \
    P##3 = *(const i32x4*)&lds[S][1][bbase + 3072]; } while (0)
#define READF(SET, S) do { \
    RDA(aA##SET, S, 0); RDB(bA##SET, S); RDA(aC##SET, S, 1); } while (0)
#define MF(ACC, A, B) do { \
    ACC[0][0] = __builtin_amdgcn_mfma_i32_16x16x64_i8(A##0, B##0, ACC[0][0], 0, 0, 0); \
    ACC[0][1] = __builtin_amdgcn_mfma_i32_16x16x64_i8(A##0, B##1, ACC[0][1], 0, 0, 0); \
    ACC[0][2] = __builtin_amdgcn_mfma_i32_16x16x64_i8(A##0, B##2, ACC[0][2], 0, 0, 0); \
    ACC[0][3] = __builtin_amdgcn_mfma_i32_16x16x64_i8(A##0, B##3, ACC[0][3], 0, 0, 0); \
    ACC[1][0] = __builtin_amdgcn_mfma_i32_16x16x64_i8(A##1, B##0, ACC[1][0], 0, 0, 0); \
    ACC[1][1] = __builtin_amdgcn_mfma_i32_16x16x64_i8(A##1, B##1, ACC[1][1], 0, 0, 0); \
    ACC[1][2] = __builtin_amdgcn_mfma_i32_16x16x64_i8(A##1, B##2, ACC[1][2], 0, 0, 0); \
    ACC[1][3] = __builtin_amdgcn_mfma_i32_16x16x64_i8(A##1, B##3, ACC[1][3], 0, 0, 0); \
    ACC[2][0] = __builtin_amdgcn_mfma_i32_16x16x64_i8(A##2, B##0, ACC[2][0], 0, 0, 0); \
    ACC[2][1] = __builtin_amdgcn_mfma_i32_16x16x64_i8(A##2, B##1, ACC[2][1], 0, 0, 0); \
    ACC[2][2] = __builtin_amdgcn_mfma_i32_16x16x64_i8(A##2, B##2, ACC[2][2], 0, 0, 0); \
    ACC[2][3] = __builtin_amdgcn_mfma_i32_16x16x64_i8(A##2, B##3, ACC[2][3], 0, 0, 0); \
    ACC[3][0] = __builtin_amdgcn_mfma_i32_16x16x64_i8(A##3, B##0, ACC[3][0], 0, 0, 0); \
    ACC[3][1] = __builtin_amdgcn_mfma_i32_16x16x64_i8(A##3, B##1, ACC[3][1], 0, 0, 0); \
    ACC[3][2] = __builtin_amdgcn_mfma_i32_16x16x64_i8(A##3, B##2, ACC[3][2], 0, 0, 0); \
    ACC[3][3] = __builtin_amdgcn_mfma_i32_16x16x64_i8(A##3, B##3, ACC[3][3], 0, 0, 0); } while (0)

// Window for tile in slot S consuming frag set CUR; stage tile TT (iff ST);
// read tile at slot (S+1)&3 into set NXT interleaved with the MFMA cluster (iff RD).
#define WIN(S, CUR, NXT, ST, TT, HASVM, VN, RD) do { \
    if (ST) STAGE4((S + 3) & 3, TT); \
    if (HASVM) { VMWS(VN); } \
    BARS(); \
    __builtin_amdgcn_s_setprio(1); \
    MF(acc0, aA##CUR, bA##CUR); \
    __builtin_amdgcn_s_setprio(0); \
    if (RD) READF(NXT, (S + 1) & 3); \
    __builtin_amdgcn_s_setprio(1); \
    MF(acc1, aC##CUR, bA##CUR); \
    __builtin_amdgcn_s_setprio(0); \
  } while (0)

  // prologue: stage tiles 0,1,2 into slots 0,1,2; drain tile 0; barrier;
  // read tile 0 into set e (one-time serial exposure).
  STAGE4(0, 0);
  STAGE4(1, 1);
  STAGE4(2, 2);
  VMWS(8);        // in-flight 0,1,2 -> drains tile 0
  BARS();         // global guarantee for tile 0
  READF(e, 0);

  int kt = 0;
  for (; kt + 8 <= nK; kt += 4) {
    WIN(0, e, o, 1, kt + 3, 1, 8, 1);
    WIN(1, o, e, 1, kt + 4, 1, 8, 1);
    WIN(2, e, o, 1, kt + 5, 1, 8, 1);
    WIN(3, o, e, 1, kt + 6, 1, 8, 1);
  }
  // kt == nK-4 (nK % 4 == 0). Window nK-4 stages the last tile.
  WIN(0, e, o, 1, nK - 1, 1, 8, 1);   // drains nK-3; reads nK-3 -> o
  WIN(1, o, e, 0, 0, 1, 4, 1);        // drains nK-2; reads nK-2 -> e
  WIN(2, e, o, 0, 0, 1, 0, 1);        // drains nK-1; reads nK-1 -> o
  WIN(3, o, e, 0, 0, 0, 0, 0);        // consume o; nothing to read

  // ---------------- epilogue: scale + bias, store Y, per-row |y| max ----------------
  float swv[4], biv[4];
  size_t gcolv[4];
  #pragma unroll
  for (int j = 0; j < 4; ++j) {
    gcolv[j] = bcol + wc * 64 + j * 16 + l16;
    swv[j] = sw[gcolv[j]];
    biv[j] = bias[gcolv[j]];
  }
  #pragma unroll
  for (int mh = 0; mh < 2; ++mh) {
    #pragma unroll
    for (int i = 0; i < 4; ++i) {
      #pragma unroll
      for (int r = 0; r < 4; ++r) {
        const size_t grow = brow + (size_t)(wr * 128 + mh * 64 + i * 16 + g4 * 4 + r);
        const float sxr = sx[grow];
        float* yrow = Y + grow * (size_t)N;
        float rmax = 0.0f;
        #pragma unroll
        for (int j = 0; j < 4; ++j) {
          const int av = mh ? acc1[i][j][r] : acc0[i][j][r];
          const float y = (float)av * (sxr * swv[j]) + biv[j];
          yrow[gcolv[j]] = y;
          rmax = fmaxf(rmax, fabsf(y));
        }
        rmax = fmaxf(rmax, __shfl_xor(rmax, 1));
        rmax = fmaxf(rmax, __shfl_xor(rmax, 2));
        rmax = fmaxf(rmax, __shfl_xor(rmax, 4));
        rmax = fmaxf(rmax, __shfl_xor(rmax, 8));
        if (l16 == 0)
          atomicMax(&rowmax[grow], __float_as_uint(rmax));
      }
    }
  }
#undef STAGE4
#undef BARS
#undef VMWS
#undef RDA
#undef RDB
#undef READF
#undef MF
#undef WIN
}

// ---------------- in-place per-row output fake-quant ----------------
__global__ __launch_bounds__(256) void outquant_kernel(
    float* __restrict__ Y, const unsigned int* __restrict__ rowmax, int N)
{
  const size_t row = blockIdx.x;
  const float amax = __uint_as_float(rowmax[row]);
  const float scale = fmaxf(amax, 1e-5f) * (1.0f / 127.0f);
  float* __restrict__ p = Y + row * (size_t)N;
  const int nv = N >> 2;
  for (int i = threadIdx.x; i < nv; i += 256) {
    float4 v = ((float4*)p)[i];
    v.x = rintf(v.x / scale) * scale;
    v.y = rintf(v.y / scale) * scale;
    v.z = rintf(v.z / scale) * scale;
    v.w = rintf(v.w / scale) * scale;
    ((float4*)p)[i] = v;
  }
}

extern "C" void kernel_launch(void* const* d_in, const int* in_sizes, int n_in,
                              void* d_out, int out_size, void* d_ws, size_t ws_size,
                              hipStream_t stream)
{
  const float* x = (const float*)d_in[0];   // [B,S,D_in] fp32
  const float* wgt = (const float*)d_in[1]; // [D_out,D_in] fp32
  const float* bias = (const float*)d_in[2];// [D_out] fp32
  float* out = (float*)d_out;               // [B,S,D_out] fp32

  const int N = in_sizes[2];                // D_out
  const int K = in_sizes[1] / N;            // D_in
  const int M = in_sizes[0] / K;            // B*S

  char* ws = (char*)d_ws;
  signed char* qx = (signed char*)ws;  ws += (size_t)M * K;         // i8
  signed char* qw = (signed char*)ws;  ws += (size_t)N * K;         // i8
  float* sx = (float*)ws;              ws += (size_t)M * sizeof(float);
  float* sw = (float*)ws;              ws += (size_t)N * sizeof(float);
  unsigned int* rowmax = (unsigned int*)ws;

  hipMemsetAsync(rowmax, 0, (size_t)M * sizeof(unsigned int), stream);

  if (K == 4096) {
    quant_rows4096_dual_kernel<<<M + N, 256, 0, stream>>>(
        x, wgt, (u32*)qx, (u32*)qw, sx, sw, M);
  } else {
    quant_rows_kernel<<<M, 256, 0, stream>>>(x, (u32*)qx, sx, K);
    quant_rows_kernel<<<N, 256, 0, stream>>>(wgt, (u32*)qw, sw, K);
  }

  const int grid = (M / BM) * (N / BN);
  gemm_bt_kernel<<<grid, 512, 0, stream>>>(qx, qw, sx, sw, bias, out, rowmax, M, N, K);

  outquant_kernel<<<M, 256, 0, stream>>>(out, rowmax, N);
}

// Round 19
// 245.070 us; speedup vs baseline: 1.1750x; 1.1750x over previous
//
#include <hip/hip_runtime.h>

typedef unsigned int u32;
typedef __attribute__((ext_vector_type(4))) int i32x4;   // 16 i8 (A/B frag) or 4 i32 (C/D)

#define BM 256
#define BN 256
#define BKT 64    // K elements (i8) per K-tile; LDS row = 64 B, paired-row swizzle

__device__ __forceinline__ void gload16(const void* g, void* l) {
  __builtin_amdgcn_global_load_lds(
      (const __attribute__((address_space(1))) unsigned int*)g,
      (__attribute__((address_space(3))) unsigned int*)l, 16, 0, 0);
}

__device__ __forceinline__ u32 pack4_i8(float4 v, float scale) {
  const int a = (int)rintf(v.x / scale);
  const int b = (int)rintf(v.y / scale);
  const int c = (int)rintf(v.z / scale);
  const int d = (int)rintf(v.w / scale);
  return (u32)(a & 255) | (((u32)(b & 255)) << 8) |
         (((u32)(c & 255)) << 16) | (((u32)(d & 255)) << 24);
}

// ------- per-row fake-quant -> int8, single-pass, X and W merged in one grid -------
__global__ __launch_bounds__(256) void quant_rows4096_dual_kernel(
    const float* __restrict__ xsrc, const float* __restrict__ wsrc,
    u32* __restrict__ qx, u32* __restrict__ qw,
    float* __restrict__ sx, float* __restrict__ sw, int mrows)
{
  const int bid = (int)blockIdx.x;
  const float* __restrict__ src;
  u32* __restrict__ q;
  float* __restrict__ scales;
  size_t row;
  if (bid < mrows) { src = xsrc; q = qx; scales = sx; row = (size_t)bid; }
  else             { src = wsrc; q = qw; scales = sw; row = (size_t)(bid - mrows); }

  const float4* __restrict__ p = (const float4*)(src + row * 4096);
  const int t = threadIdx.x;
  float4 v0 = p[t];
  float4 v1 = p[t + 256];
  float4 v2 = p[t + 512];
  float4 v3 = p[t + 768];
  float m = 0.0f;
  m = fmaxf(m, fmaxf(fmaxf(fabsf(v0.x), fabsf(v0.y)), fmaxf(fabsf(v0.z), fabsf(v0.w))));
  m = fmaxf(m, fmaxf(fmaxf(fabsf(v1.x), fabsf(v1.y)), fmaxf(fabsf(v1.z), fabsf(v1.w))));
  m = fmaxf(m, fmaxf(fmaxf(fabsf(v2.x), fabsf(v2.y)), fmaxf(fabsf(v2.z), fabsf(v2.w))));
  m = fmaxf(m, fmaxf(fmaxf(fabsf(v3.x), fabsf(v3.y)), fmaxf(fabsf(v3.z), fabsf(v3.w))));
  #pragma unroll
  for (int off = 32; off > 0; off >>= 1) m = fmaxf(m, __shfl_xor(m, off));
  __shared__ float wmax[4];
  if ((t & 63) == 0) wmax[t >> 6] = m;
  __syncthreads();
  m = fmaxf(fmaxf(wmax[0], wmax[1]), fmaxf(wmax[2], wmax[3]));
  const float scale = fmaxf(m, 1e-5f) * (1.0f / 127.0f);
  if (t == 0) scales[row] = scale;
  u32* __restrict__ qp = q + row * 1024;
  qp[t]       = pack4_i8(v0, scale);
  qp[t + 256] = pack4_i8(v1, scale);
  qp[t + 512] = pack4_i8(v2, scale);
  qp[t + 768] = pack4_i8(v3, scale);
}

// generic fallback (any K multiple of 4)
__global__ __launch_bounds__(256) void quant_rows_kernel(
    const float* __restrict__ src, u32* __restrict__ q,
    float* __restrict__ scales, int K)
{
  const size_t row = blockIdx.x;
  const float* __restrict__ p = src + row * (size_t)K;
  const int t = threadIdx.x;
  const int nv = K >> 2;
  float m = 0.0f;
  for (int i = t; i < nv; i += 256) {
    float4 v = ((const float4*)p)[i];
    m = fmaxf(m, fmaxf(fmaxf(fabsf(v.x), fabsf(v.y)),
                       fmaxf(fabsf(v.z), fabsf(v.w))));
  }
  #pragma unroll
  for (int off = 32; off > 0; off >>= 1) m = fmaxf(m, __shfl_xor(m, off));
  __shared__ float wmax[4];
  if ((t & 63) == 0) wmax[t >> 6] = m;
  __syncthreads();
  m = fmaxf(fmaxf(wmax[0], wmax[1]), fmaxf(wmax[2], wmax[3]));
  const float scale = fmaxf(m, 1e-5f) * (1.0f / 127.0f);
  if (t == 0) scales[row] = scale;
  u32* __restrict__ qp = q + row * ((size_t)K >> 2);
  for (int i = t; i < nv; i += 256) {
    float4 v = ((const float4*)p)[i];
    qp[i] = pack4_i8(v, scale);
  }
}

// ------- 256x256 8-wave i8 GEMM, BK=64, QUAD-buffered LDS, 1 barrier/K-tile -------
// (R13 — session best: ~158-166 us GEMM, ~1700 TOPS, 0 bank conflicts)
// C = Aq(MxK) * Bq(NxK)^T, exact i32 accumulate via mfma_i32_16x16x64_i8.
// LDS: 4 slots x (A 256x64B + B 256x64B) = 128 KiB.
// Paired-row swizzle: physical 128B window = row-pair rp=r>>1; 16B slot index
//   sp = ((c>>4) + ((r&1)<<2)) ^ (rp&7).  2-way banked reads (free, m136).
// Window t: { STAGE4(tile t+3 -> slot (t+3)&3); 12 ds_reads(tile t, slot t&3);
//             VMW(8); BAR; 32 MFMA }.
// Ledger: 3 tiles in flight x 4 ops; VMW(8) at window t drains the oldest (the
// tile read next window), guaranteed globally at BAR. WAR: stage target slot
// (t+3)&3 = (t-1)&3 was consumed in window t-1. nK%4==0, nK>=8.
__global__ __launch_bounds__(512, 2) void gemm_bt_kernel(
    const signed char* __restrict__ Aq, const signed char* __restrict__ Bq,
    const float* __restrict__ sx, const float* __restrict__ sw,
    const float* __restrict__ bias, float* __restrict__ Y,
    unsigned int* __restrict__ rowmax, int M, int N, int K)
{
  __shared__ signed char lds[4][2][BM * 64];   // [slot][A/B], 16 KiB regions

  int bid = (int)blockIdx.x;
  const int nwg = (int)gridDim.x;
  if ((nwg & 7) == 0) {                 // bijective XCD swizzle
    const int cpx = nwg >> 3;
    bid = (bid & 7) * cpx + (bid >> 3);
  }
  const int ntile = N / BN;
  const size_t brow = (size_t)(bid / ntile) * BM;
  const size_t bcol = (size_t)(bid % ntile) * BN;

  const int t = threadIdx.x;
  const int lane = t & 63;
  const int wid = t >> 6;
  const int wr = wid >> 2, wc = wid & 3;       // 2(M) x 4(N) wave grid
  const int g4 = lane >> 4, l16 = lane & 15;

  // ds_read per-lane constants: parity = l16&1, w8 = (l16>>1)&7,
  // sp = (g4 + parity*4) ^ w8 ; byte = rp*128 + sp*16.
  const int parity = l16 & 1;
  const int w8 = (l16 >> 1) & 7;
  const int sp = (g4 + (parity << 2)) ^ w8;
  const int abase = (wr * 64 + (l16 >> 1)) * 128 + sp * 16;  // + mh*4096 + i*1024
  const int bbase = (wc * 32 + (l16 >> 1)) * 128 + sp * 16;  // + j*1024

  // staging: thread t -> linear LDS dst byte t*16 (+round*8192); inverse map:
  // q = (t&7) ^ ((t>>3)&7); row = 2*(t>>3) + (q>>2); col = (q&3)*16.
  const int q0 = (t & 7) ^ ((t >> 3) & 7);
  const int srow = 2 * (t >> 3) + (q0 >> 2);          // 0..127
  const int scol = (q0 & 3) * 16;
  const signed char* srcA = Aq + (brow + srow) * (size_t)K + scol;
  const signed char* srcB = Bq + (bcol + srow) * (size_t)K + scol;
  const int dstb = t * 16;

  i32x4 acc0[4][4] = {};   // mh0 (rows wr*128 + 0..63), exact i32
  i32x4 acc1[4][4] = {};   // mh1 (rows wr*128 + 64..127)
  const int nK = K / BKT;

  i32x4 aA0, aA1, aA2, aA3;   // A frags mh0
  i32x4 aC0, aC1, aC2, aC3;   // A frags mh1
  i32x4 bA0, bA1, bA2, bA3;   // B frags

#define STAGE4(S, TT) do { \
    gload16(srcA + (size_t)(TT) * 64,                      &lds[S][0][dstb]); \
    gload16(srcA + 128 * (size_t)K + (size_t)(TT) * 64,    &lds[S][0][8192 + dstb]); \
    gload16(srcB + (size_t)(TT) * 64,                      &lds[S][1][dstb]); \
    gload16(srcB + 128 * (size_t)K + (size_t)(TT) * 64,    &lds[S][1][8192 + dstb]); \
  } while (0)
#define BARS() do { asm volatile("" ::: "memory"); \
                    __builtin_amdgcn_s_barrier(); \
                    asm volatile("" ::: "memory"); } while (0)
#define VMWS(NN) asm volatile("s_waitcnt vmcnt(" #NN ")" ::: "memory")
#define RDA(P, S, MH) do { \
    P##0 = *(const i32x4*)&lds[S][0][abase + (MH) * 4096 +    0]; \
    P##1 = *(const i32x4*)&lds[S][0][abase + (MH) * 4096 + 1024]; \
    P##2 = *(const i32x4*)&lds[S][0][abase + (MH) * 4096 + 2048]; \
    P##3 = *(const i32x4*)&lds[S][0][abase + (MH) * 4096 + 3072]; } while (0)
#define RDB(P, S) do { \
    P##0 = *(const i32x4*)&lds[S][1][bbase +    0]; \
    P##1 = *(const i32x4*)&lds[S][1][bbase + 1024]; \
    P##2 = *(const i32x4*)&lds[S][1][bbase + 2048]; \
    P##3 = *(const i32x4*)&lds[S][1][bbase + 3072]; } while (0)
#define MF(ACC, A, B) do { \
    ACC[0][0] = __builtin_amdgcn_mfma_i32_16x16x64_i8(A##0, B##0, ACC[0][0], 0, 0, 0); \
    ACC[0][1] = __builtin_amdgcn_mfma_i32_16x16x64_i8(A##0, B##1, ACC[0][1], 0, 0, 0); \
    ACC[0][2] = __builtin_amdgcn_mfma_i32_16x16x64_i8(A##0, B##2, ACC[0][2], 0, 0, 0); \
    ACC[0][3] = __builtin_amdgcn_mfma_i32_16x16x64_i8(A##0, B##3, ACC[0][3], 0, 0, 0); \
    ACC[1][0] = __builtin_amdgcn_mfma_i32_16x16x64_i8(A##1, B##0, ACC[1][0], 0, 0, 0); \
    ACC[1][1] = __builtin_amdgcn_mfma_i32_16x16x64_i8(A##1, B##1, ACC[1][1], 0, 0, 0); \
    ACC[1][2] = __builtin_amdgcn_mfma_i32_16x16x64_i8(A##1, B##2, ACC[1][2], 0, 0, 0); \
    ACC[1][3] = __builtin_amdgcn_mfma_i32_16x16x64_i8(A##1, B##3, ACC[1][3], 0, 0, 0); \
    ACC[2][0] = __builtin_amdgcn_mfma_i32_16x16x64_i8(A##2, B##0, ACC[2][0], 0, 0, 0); \
    ACC[2][1] = __builtin_amdgcn_mfma_i32_16x16x64_i8(A##2, B##1, ACC[2][1], 0, 0, 0); \
    ACC[2][2] = __builtin_amdgcn_mfma_i32_16x16x64_i8(A##2, B##2, ACC[2][2], 0, 0, 0); \
    ACC[2][3] = __builtin_amdgcn_mfma_i32_16x16x64_i8(A##2, B##3, ACC[2][3], 0, 0, 0); \
    ACC[3][0] = __builtin_amdgcn_mfma_i32_16x16x64_i8(A##3, B##0, ACC[3][0], 0, 0, 0); \
    ACC[3][1] = __builtin_amdgcn_mfma_i32_16x16x64_i8(A##3, B##1, ACC[3][1], 0, 0, 0); \
    ACC[3][2] = __builtin_amdgcn_mfma_i32_16x16x64_i8(A##3, B##2, ACC[3][2], 0, 0, 0); \
    ACC[3][3] = __builtin_amdgcn_mfma_i32_16x16x64_i8(A##3, B##3, ACC[3][3], 0, 0, 0); } while (0)

// Window for tile in slot S: stage tile TT into slot (S+3)&3 (iff ST), read tile
// in slot S BEFORE the barrier, drain with VMW(VN), barrier, then 32 MFMA.
#define WIN(S, ST, TT, HASVM, VN) do { \
    if (ST) STAGE4((S + 3) & 3, TT); \
    RDA(aA, S, 0); \
    RDB(bA, S); \
    RDA(aC, S, 1); \
    if (HASVM) { VMWS(VN); } \
    BARS(); \
    __builtin_amdgcn_s_setprio(1); \
    MF(acc0, aA, bA); \
    MF(acc1, aC, bA); \
    __builtin_amdgcn_s_setprio(0); \
  } while (0)

  // prologue: stage tiles 0,1,2 into slots 0,1,2; drain tile 0; barrier.
  STAGE4(0, 0);
  STAGE4(1, 1);
  STAGE4(2, 2);
  VMWS(8);        // in-flight 0,1,2 -> drains tile 0
  BARS();         // global guarantee for tile 0

  int kt = 0;
  for (; kt + 8 <= nK; kt += 4) {
    WIN(0, 1, kt + 3, 1, 8);
    WIN(1, 1, kt + 4, 1, 8);
    WIN(2, 1, kt + 5, 1, 8);
    WIN(3, 1, kt + 6, 1, 8);
  }
  // kt == nK-4 (nK % 4 == 0). Window nK-4 stages the last tile.
  WIN(0, 1, nK - 1, 1, 8);   // drains nK-3
  WIN(1, 0, 0, 1, 4);        // drains nK-2
  WIN(2, 0, 0, 1, 0);        // drains nK-1
  WIN(3, 0, 0, 0, 0);        // guaranteed by previous window's VMW(0)+BAR

  // ---------------- epilogue: scale + bias, store Y, per-row |y| max ----------------
  float swv[4], biv[4];
  size_t gcolv[4];
  #pragma unroll
  for (int j = 0; j < 4; ++j) {
    gcolv[j] = bcol + wc * 64 + j * 16 + l16;
    swv[j] = sw[gcolv[j]];
    biv[j] = bias[gcolv[j]];
  }
  #pragma unroll
  for (int mh = 0; mh < 2; ++mh) {
    #pragma unroll
    for (int i = 0; i < 4; ++i) {
      #pragma unroll
      for (int r = 0; r < 4; ++r) {
        const size_t grow = brow + (size_t)(wr * 128 + mh * 64 + i * 16 + g4 * 4 + r);
        const float sxr = sx[grow];
        float* yrow = Y + grow * (size_t)N;
        float rmax = 0.0f;
        #pragma unroll
        for (int j = 0; j < 4; ++j) {
          const int av = mh ? acc1[i][j][r] : acc0[i][j][r];
          const float y = (float)av * (sxr * swv[j]) + biv[j];
          yrow[gcolv[j]] = y;
          rmax = fmaxf(rmax, fabsf(y));
        }
        rmax = fmaxf(rmax, __shfl_xor(rmax, 1));
        rmax = fmaxf(rmax, __shfl_xor(rmax, 2));
        rmax = fmaxf(rmax, __shfl_xor(rmax, 4));
        rmax = fmaxf(rmax, __shfl_xor(rmax, 8));
        if (l16 == 0)
          atomicMax(&rowmax[grow], __float_as_uint(rmax));
      }
    }
  }
#undef STAGE4
#undef BARS
#undef VMWS
#undef RDA
#undef RDB
#undef MF
#undef WIN
}

// ---------------- in-place per-row output fake-quant ----------------
__global__ __launch_bounds__(256) void outquant_kernel(
    float* __restrict__ Y, const unsigned int* __restrict__ rowmax, int N)
{
  const size_t row = blockIdx.x;
  const float amax = __uint_as_float(rowmax[row]);
  const float scale = fmaxf(amax, 1e-5f) * (1.0f / 127.0f);
  float* __restrict__ p = Y + row * (size_t)N;
  const int nv = N >> 2;
  for (int i = threadIdx.x; i < nv; i += 256) {
    float4 v = ((float4*)p)[i];
    v.x = rintf(v.x / scale) * scale;
    v.y = rintf(v.y / scale) * scale;
    v.z = rintf(v.z / scale) * scale;
    v.w = rintf(v.w / scale) * scale;
    ((float4*)p)[i] = v;
  }
}

extern "C" void kernel_launch(void* const* d_in, const int* in_sizes, int n_in,
                              void* d_out, int out_size, void* d_ws, size_t ws_size,
                              hipStream_t stream)
{
  const float* x = (const float*)d_in[0];   // [B,S,D_in] fp32
  const float* wgt = (const float*)d_in[1]; // [D_out,D_in] fp32
  const float* bias = (const float*)d_in[2];// [D_out] fp32
  float* out = (float*)d_out;               // [B,S,D_out] fp32

  const int N = in_sizes[2];                // D_out
  const int K = in_sizes[1] / N;            // D_in
  const int M = in_sizes[0] / K;            // B*S

  char* ws = (char*)d_ws;
  signed char* qx = (signed char*)ws;  ws += (size_t)M * K;         // i8
  signed char* qw = (signed char*)ws;  ws += (size_t)N * K;         // i8
  float* sx = (float*)ws;              ws += (size_t)M * sizeof(float);
  float* sw = (float*)ws;              ws += (size_t)N * sizeof(float);
  unsigned int* rowmax = (unsigned int*)ws;

  hipMemsetAsync(rowmax, 0, (size_t)M * sizeof(unsigned int), stream);

  if (K == 4096) {
    quant_rows4096_dual_kernel<<<M + N, 256, 0, stream>>>(
        x, wgt, (u32*)qx, (u32*)qw, sx, sw, M);
  } else {
    quant_rows_kernel<<<M, 256, 0, stream>>>(x, (u32*)qx, sx, K);
    quant_rows_kernel<<<N, 256, 0, stream>>>(wgt, (u32*)qw, sw, K);
  }

  const int grid = (M / BM) * (N / BN);
  gemm_bt_kernel<<<grid, 512, 0, stream>>>(qx, qw, sx, sw, bias, out, rowmax, M, N, K);

  outquant_kernel<<<M, 256, 0, stream>>>(out, rowmax, N);
}

// Round 20
// 244.831 us; speedup vs baseline: 1.1762x; 1.0010x over previous
//
#include <hip/hip_runtime.h>
#include <hip/hip_fp16.h>

typedef unsigned int u32;
typedef unsigned short u16;
typedef __attribute__((ext_vector_type(4))) int i32x4;   // 16 i8 (A/B frag) or 4 i32 (C/D)

#define BM 256
#define BN 256
#define BKT 64    // K elements (i8) per K-tile; LDS row = 64 B, paired-row swizzle

__device__ __forceinline__ void gload16(const void* g, void* l) {
  __builtin_amdgcn_global_load_lds(
      (const __attribute__((address_space(1))) unsigned int*)g,
      (__attribute__((address_space(3))) unsigned int*)l, 16, 0, 0);
}

__device__ __forceinline__ u32 pack4_i8(float4 v, float scale) {
  const int a = (int)rintf(v.x / scale);
  const int b = (int)rintf(v.y / scale);
  const int c = (int)rintf(v.z / scale);
  const int d = (int)rintf(v.w / scale);
  return (u32)(a & 255) | (((u32)(b & 255)) << 8) |
         (((u32)(c & 255)) << 16) | (((u32)(d & 255)) << 24);
}

// ------- per-row fake-quant -> int8, single-pass, X and W merged in one grid -------
__global__ __launch_bounds__(256) void quant_rows4096_dual_kernel(
    const float* __restrict__ xsrc, const float* __restrict__ wsrc,
    u32* __restrict__ qx, u32* __restrict__ qw,
    float* __restrict__ sx, float* __restrict__ sw, int mrows)
{
  const int bid = (int)blockIdx.x;
  const float* __restrict__ src;
  u32* __restrict__ q;
  float* __restrict__ scales;
  size_t row;
  if (bid < mrows) { src = xsrc; q = qx; scales = sx; row = (size_t)bid; }
  else             { src = wsrc; q = qw; scales = sw; row = (size_t)(bid - mrows); }

  const float4* __restrict__ p = (const float4*)(src + row * 4096);
  const int t = threadIdx.x;
  float4 v0 = p[t];
  float4 v1 = p[t + 256];
  float4 v2 = p[t + 512];
  float4 v3 = p[t + 768];
  float m = 0.0f;
  m = fmaxf(m, fmaxf(fmaxf(fabsf(v0.x), fabsf(v0.y)), fmaxf(fabsf(v0.z), fabsf(v0.w))));
  m = fmaxf(m, fmaxf(fmaxf(fabsf(v1.x), fabsf(v1.y)), fmaxf(fabsf(v1.z), fabsf(v1.w))));
  m = fmaxf(m, fmaxf(fmaxf(fabsf(v2.x), fabsf(v2.y)), fmaxf(fabsf(v2.z), fabsf(v2.w))));
  m = fmaxf(m, fmaxf(fmaxf(fabsf(v3.x), fabsf(v3.y)), fmaxf(fabsf(v3.z), fabsf(v3.w))));
  #pragma unroll
  for (int off = 32; off > 0; off >>= 1) m = fmaxf(m, __shfl_xor(m, off));
  __shared__ float wmax[4];
  if ((t & 63) == 0) wmax[t >> 6] = m;
  __syncthreads();
  m = fmaxf(fmaxf(wmax[0], wmax[1]), fmaxf(wmax[2], wmax[3]));
  const float scale = fmaxf(m, 1e-5f) * (1.0f / 127.0f);
  if (t == 0) scales[row] = scale;
  u32* __restrict__ qp = q + row * 1024;
  qp[t]       = pack4_i8(v0, scale);
  qp[t + 256] = pack4_i8(v1, scale);
  qp[t + 512] = pack4_i8(v2, scale);
  qp[t + 768] = pack4_i8(v3, scale);
}

// generic fallback (any K multiple of 4)
__global__ __launch_bounds__(256) void quant_rows_kernel(
    const float* __restrict__ src, u32* __restrict__ q,
    float* __restrict__ scales, int K)
{
  const size_t row = blockIdx.x;
  const float* __restrict__ p = src + row * (size_t)K;
  const int t = threadIdx.x;
  const int nv = K >> 2;
  float m = 0.0f;
  for (int i = t; i < nv; i += 256) {
    float4 v = ((const float4*)p)[i];
    m = fmaxf(m, fmaxf(fmaxf(fabsf(v.x), fabsf(v.y)),
                       fmaxf(fabsf(v.z), fabsf(v.w))));
  }
  #pragma unroll
  for (int off = 32; off > 0; off >>= 1) m = fmaxf(m, __shfl_xor(m, off));
  __shared__ float wmax[4];
  if ((t & 63) == 0) wmax[t >> 6] = m;
  __syncthreads();
  m = fmaxf(fmaxf(wmax[0], wmax[1]), fmaxf(wmax[2], wmax[3]));
  const float scale = fmaxf(m, 1e-5f) * (1.0f / 127.0f);
  if (t == 0) scales[row] = scale;
  u32* __restrict__ qp = q + row * ((size_t)K >> 2);
  for (int i = t; i < nv; i += 256) {
    float4 v = ((const float4*)p)[i];
    qp[i] = pack4_i8(v, scale);
  }
}

// ------- 256x256 8-wave i8 GEMM, BK=64, QUAD-buffered LDS, 1 barrier/K-tile -------
// (R13 structure — session best. Template switches the epilogue store only:
//  U16=1 stores y as fp16 to Y16 (half traffic, outquant16 expands), U16=0
//  stores fp32 to Y. rowmax is always computed from exact fp32 y.)
__global__ __launch_bounds__(512, 2) void gemm_bt_kernel(
    const signed char* __restrict__ Aq, const signed char* __restrict__ Bq,
    const float* __restrict__ sx, const float* __restrict__ sw,
    const float* __restrict__ bias, float* __restrict__ Y,
    __half* __restrict__ Y16, int use16,
    unsigned int* __restrict__ rowmax, int M, int N, int K)
{
  __shared__ signed char lds[4][2][BM * 64];   // [slot][A/B], 16 KiB regions

  int bid = (int)blockIdx.x;
  const int nwg = (int)gridDim.x;
  if ((nwg & 7) == 0) {                 // bijective XCD swizzle
    const int cpx = nwg >> 3;
    bid = (bid & 7) * cpx + (bid >> 3);
  }
  const int ntile = N / BN;
  const size_t brow = (size_t)(bid / ntile) * BM;
  const size_t bcol = (size_t)(bid % ntile) * BN;

  const int t = threadIdx.x;
  const int lane = t & 63;
  const int wid = t >> 6;
  const int wr = wid >> 2, wc = wid & 3;       // 2(M) x 4(N) wave grid
  const int g4 = lane >> 4, l16 = lane & 15;

  // ds_read per-lane constants: parity = l16&1, w8 = (l16>>1)&7,
  // sp = (g4 + parity*4) ^ w8 ; byte = rp*128 + sp*16.
  const int parity = l16 & 1;
  const int w8 = (l16 >> 1) & 7;
  const int sp = (g4 + (parity << 2)) ^ w8;
  const int abase = (wr * 64 + (l16 >> 1)) * 128 + sp * 16;  // + mh*4096 + i*1024
  const int bbase = (wc * 32 + (l16 >> 1)) * 128 + sp * 16;  // + j*1024

  // staging: thread t -> linear LDS dst byte t*16 (+round*8192); inverse map:
  // q = (t&7) ^ ((t>>3)&7); row = 2*(t>>3) + (q>>2); col = (q&3)*16.
  const int q0 = (t & 7) ^ ((t >> 3) & 7);
  const int srow = 2 * (t >> 3) + (q0 >> 2);          // 0..127
  const int scol = (q0 & 3) * 16;
  const signed char* srcA = Aq + (brow + srow) * (size_t)K + scol;
  const signed char* srcB = Bq + (bcol + srow) * (size_t)K + scol;
  const int dstb = t * 16;

  i32x4 acc0[4][4] = {};   // mh0 (rows wr*128 + 0..63), exact i32
  i32x4 acc1[4][4] = {};   // mh1 (rows wr*128 + 64..127)
  const int nK = K / BKT;

  i32x4 aA0, aA1, aA2, aA3;   // A frags mh0
  i32x4 aC0, aC1, aC2, aC3;   // A frags mh1
  i32x4 bA0, bA1, bA2, bA3;   // B frags

#define STAGE4(S, TT) do { \
    gload16(srcA + (size_t)(TT) * 64,                      &lds[S][0][dstb]); \
    gload16(srcA + 128 * (size_t)K + (size_t)(TT) * 64,    &lds[S][0][8192 + dstb]); \
    gload16(srcB + (size_t)(TT) * 64,                      &lds[S][1][dstb]); \
    gload16(srcB + 128 * (size_t)K + (size_t)(TT) * 64,    &lds[S][1][8192 + dstb]); \
  } while (0)
#define BARS() do { asm volatile("" ::: "memory"); \
                    __builtin_amdgcn_s_barrier(); \
                    asm volatile("" ::: "memory"); } while (0)
#define VMWS(NN) asm volatile("s_waitcnt vmcnt(" #NN ")" ::: "memory")
#define RDA(P, S, MH) do { \
    P##0 = *(const i32x4*)&lds[S][0][abase + (MH) * 4096 +    0]; \
    P##1 = *(const i32x4*)&lds[S][0][abase + (MH) * 4096 + 1024]; \
    P##2 = *(const i32x4*)&lds[S][0][abase + (MH) * 4096 + 2048]; \
    P##3 = *(const i32x4*)&lds[S][0][abase + (MH) * 4096 + 3072]; } while (0)
#define RDB(P, S) do { \
    P##0 = *(const i32x4*)&lds[S][1][bbase +    0]; \
    P##1 = *(const i32x4*)&lds[S][1][bbase + 1024]; \
    P##2 = *(const i32x4*)&lds[S][1][bbase + 2048]; \
    P##3 = *(const i32x4*)&lds[S][1][bbase + 3072]; } while (0)
#define MF(ACC, A, B) do { \
    ACC[0][0] = __builtin_amdgcn_mfma_i32_16x16x64_i8(A##0, B##0, ACC[0][0], 0, 0, 0); \
    ACC[0][1] = __builtin_amdgcn_mfma_i32_16x16x64_i8(A##0, B##1, ACC[0][1], 0, 0, 0); \
    ACC[0][2] = __builtin_amdgcn_mfma_i32_16x16x64_i8(A##0, B##2, ACC[0][2], 0, 0, 0); \
    ACC[0][3] = __builtin_amdgcn_mfma_i32_16x16x64_i8(A##0, B##3, ACC[0][3], 0, 0, 0); \
    ACC[1][0] = __builtin_amdgcn_mfma_i32_16x16x64_i8(A##1, B##0, ACC[1][0], 0, 0, 0); \
    ACC[1][1] = __builtin_amdgcn_mfma_i32_16x16x64_i8(A##1, B##1, ACC[1][1], 0, 0, 0); \
    ACC[1][2] = __builtin_amdgcn_mfma_i32_16x16x64_i8(A##1, B##2, ACC[1][2], 0, 0, 0); \
    ACC[1][3] = __builtin_amdgcn_mfma_i32_16x16x64_i8(A##1, B##3, ACC[1][3], 0, 0, 0); \
    ACC[2][0] = __builtin_amdgcn_mfma_i32_16x16x64_i8(A##2, B##0, ACC[2][0], 0, 0, 0); \
    ACC[2][1] = __builtin_amdgcn_mfma_i32_16x16x64_i8(A##2, B##1, ACC[2][1], 0, 0, 0); \
    ACC[2][2] = __builtin_amdgcn_mfma_i32_16x16x64_i8(A##2, B##2, ACC[2][2], 0, 0, 0); \
    ACC[2][3] = __builtin_amdgcn_mfma_i32_16x16x64_i8(A##2, B##3, ACC[2][3], 0, 0, 0); \
    ACC[3][0] = __builtin_amdgcn_mfma_i32_16x16x64_i8(A##3, B##0, ACC[3][0], 0, 0, 0); \
    ACC[3][1] = __builtin_amdgcn_mfma_i32_16x16x64_i8(A##3, B##1, ACC[3][1], 0, 0, 0); \
    ACC[3][2] = __builtin_amdgcn_mfma_i32_16x16x64_i8(A##3, B##2, ACC[3][2], 0, 0, 0); \
    ACC[3][3] = __builtin_amdgcn_mfma_i32_16x16x64_i8(A##3, B##3, ACC[3][3], 0, 0, 0); } while (0)

#define WIN(S, ST, TT, HASVM, VN) do { \
    if (ST) STAGE4((S + 3) & 3, TT); \
    RDA(aA, S, 0); \
    RDB(bA, S); \
    RDA(aC, S, 1); \
    if (HASVM) { VMWS(VN); } \
    BARS(); \
    __builtin_amdgcn_s_setprio(1); \
    MF(acc0, aA, bA); \
    MF(acc1, aC, bA); \
    __builtin_amdgcn_s_setprio(0); \
  } while (0)

  // prologue: stage tiles 0,1,2 into slots 0,1,2; drain tile 0; barrier.
  STAGE4(0, 0);
  STAGE4(1, 1);
  STAGE4(2, 2);
  VMWS(8);        // in-flight 0,1,2 -> drains tile 0
  BARS();         // global guarantee for tile 0

  int kt = 0;
  for (; kt + 8 <= nK; kt += 4) {
    WIN(0, 1, kt + 3, 1, 8);
    WIN(1, 1, kt + 4, 1, 8);
    WIN(2, 1, kt + 5, 1, 8);
    WIN(3, 1, kt + 6, 1, 8);
  }
  // kt == nK-4 (nK % 4 == 0). Window nK-4 stages the last tile.
  WIN(0, 1, nK - 1, 1, 8);   // drains nK-3
  WIN(1, 0, 0, 1, 4);        // drains nK-2
  WIN(2, 0, 0, 1, 0);        // drains nK-1
  WIN(3, 0, 0, 0, 0);        // guaranteed by previous window's VMW(0)+BAR

  // ---------------- epilogue: scale + bias, store y, per-row |y| max ----------------
  float swv[4], biv[4];
  size_t gcolv[4];
  #pragma unroll
  for (int j = 0; j < 4; ++j) {
    gcolv[j] = bcol + wc * 64 + j * 16 + l16;
    swv[j] = sw[gcolv[j]];
    biv[j] = bias[gcolv[j]];
  }
  #pragma unroll
  for (int mh = 0; mh < 2; ++mh) {
    #pragma unroll
    for (int i = 0; i < 4; ++i) {
      #pragma unroll
      for (int r = 0; r < 4; ++r) {
        const size_t grow = brow + (size_t)(wr * 128 + mh * 64 + i * 16 + g4 * 4 + r);
        const float sxr = sx[grow];
        float* yrow = Y + grow * (size_t)N;
        __half* yrow16 = Y16 + grow * (size_t)N;
        float rmax = 0.0f;
        #pragma unroll
        for (int j = 0; j < 4; ++j) {
          const int av = mh ? acc1[i][j][r] : acc0[i][j][r];
          const float y = (float)av * (sxr * swv[j]) + biv[j];
          if (use16) yrow16[gcolv[j]] = __float2half_rn(y);
          else       yrow[gcolv[j]] = y;
          rmax = fmaxf(rmax, fabsf(y));
        }
        rmax = fmaxf(rmax, __shfl_xor(rmax, 1));
        rmax = fmaxf(rmax, __shfl_xor(rmax, 2));
        rmax = fmaxf(rmax, __shfl_xor(rmax, 4));
        rmax = fmaxf(rmax, __shfl_xor(rmax, 8));
        if (l16 == 0)
          atomicMax(&rowmax[grow], __float_as_uint(rmax));
      }
    }
  }
#undef STAGE4
#undef BARS
#undef VMWS
#undef RDA
#undef RDB
#undef MF
#undef WIN
}

// ---------------- per-row output fake-quant: fp32 in-place ----------------
__global__ __launch_bounds__(256) void outquant_kernel(
    float* __restrict__ Y, const unsigned int* __restrict__ rowmax, int N)
{
  const size_t row = blockIdx.x;
  const float amax = __uint_as_float(rowmax[row]);
  const float scale = fmaxf(amax, 1e-5f) * (1.0f / 127.0f);
  float* __restrict__ p = Y + row * (size_t)N;
  const int nv = N >> 2;
  for (int i = threadIdx.x; i < nv; i += 256) {
    float4 v = ((float4*)p)[i];
    v.x = rintf(v.x / scale) * scale;
    v.y = rintf(v.y / scale) * scale;
    v.z = rintf(v.z / scale) * scale;
    v.w = rintf(v.w / scale) * scale;
    ((float4*)p)[i] = v;
  }
}

// ---------------- per-row output fake-quant: fp16 y -> fp32 out ----------------
__global__ __launch_bounds__(256) void outquant16_kernel(
    const __half* __restrict__ Y16, float* __restrict__ Out,
    const unsigned int* __restrict__ rowmax, int N)
{
  const size_t row = blockIdx.x;
  const float amax = __uint_as_float(rowmax[row]);
  const float scale = fmaxf(amax, 1e-5f) * (1.0f / 127.0f);
  const __half* __restrict__ p = Y16 + row * (size_t)N;
  float* __restrict__ o = Out + row * (size_t)N;
  const int nv = N >> 2;
  for (int i = threadIdx.x; i < nv; i += 256) {
    ushort4 h = ((const ushort4*)p)[i];
    float4 v;
    v.x = rintf(__half2float(__ushort_as_half(h.x)) / scale) * scale;
    v.y = rintf(__half2float(__ushort_as_half(h.y)) / scale) * scale;
    v.z = rintf(__half2float(__ushort_as_half(h.z)) / scale) * scale;
    v.w = rintf(__half2float(__ushort_as_half(h.w)) / scale) * scale;
    ((float4*)o)[i] = v;
  }
}

extern "C" void kernel_launch(void* const* d_in, const int* in_sizes, int n_in,
                              void* d_out, int out_size, void* d_ws, size_t ws_size,
                              hipStream_t stream)
{
  const float* x = (const float*)d_in[0];   // [B,S,D_in] fp32
  const float* wgt = (const float*)d_in[1]; // [D_out,D_in] fp32
  const float* bias = (const float*)d_in[2];// [D_out] fp32
  float* out = (float*)d_out;               // [B,S,D_out] fp32

  const int N = in_sizes[2];                // D_out
  const int K = in_sizes[1] / N;            // D_in
  const int M = in_sizes[0] / K;            // B*S

  char* ws = (char*)d_ws;
  signed char* qx = (signed char*)ws;  ws += (size_t)M * K;         // i8
  signed char* qw = (signed char*)ws;  ws += (size_t)N * K;         // i8
  float* sx = (float*)ws;              ws += (size_t)M * sizeof(float);
  float* sw = (float*)ws;              ws += (size_t)N * sizeof(float);
  unsigned int* rowmax = (unsigned int*)ws; ws += (size_t)M * sizeof(unsigned int);
  __half* y16 = (__half*)ws;           // optional, M*N*2 bytes

  const size_t base_need = (size_t)(ws - (char*)d_ws);
  const int use16 = (base_need + (size_t)M * N * sizeof(__half)) <= ws_size;

  hipMemsetAsync(rowmax, 0, (size_t)M * sizeof(unsigned int), stream);

  if (K == 4096) {
    quant_rows4096_dual_kernel<<<M + N, 256, 0, stream>>>(
        x, wgt, (u32*)qx, (u32*)qw, sx, sw, M);
  } else {
    quant_rows_kernel<<<M, 256, 0, stream>>>(x, (u32*)qx, sx, K);
    quant_rows_kernel<<<N, 256, 0, stream>>>(wgt, (u32*)qw, sw, K);
  }

  const int grid = (M / BM) * (N / BN);
  gemm_bt_kernel<<<grid, 512, 0, stream>>>(qx, qw, sx, sw, bias, out,
                                           y16, use16, rowmax, M, N, K);

  if (use16)
    outquant16_kernel<<<M, 256, 0, stream>>>(y16, out, rowmax, N);
  else
    outquant_kernel<<<M, 256, 0, stream>>>(out, rowmax, N);
}